// Round 1
// baseline (869.798 us; speedup 1.0000x reference)
//
#include <hip/hip_runtime.h>
#include <hip/hip_bf16.h>

#define NN 50000
#define NE 800000
#define DH 128
#define NGRAPH 512
#define NCLS 10
#define BN_EPS 1e-5f

// ---------------- CSR build ----------------

__global__ void hist_kernel(const int* __restrict__ dst, int* __restrict__ counts, int E) {
    int e = blockIdx.x * blockDim.x + threadIdx.x;
    if (e < E) atomicAdd(&counts[dst[e]], 1);
}

__global__ void compute_dinv_kernel(const int* __restrict__ counts, float* __restrict__ dinv, int N) {
    int n = blockIdx.x * blockDim.x + threadIdx.x;
    if (n < N) dinv[n] = rsqrtf((float)(counts[n] + 1));
}

__launch_bounds__(1024)
__global__ void scan_kernel(const int* __restrict__ counts, int* __restrict__ offsets,
                            int* __restrict__ cursor, int N) {
    __shared__ int partial[1024];
    int tid = threadIdx.x;
    int chunk = (N + 1023) / 1024;
    int beg = tid * chunk;
    int end = min(beg + chunk, N);
    int s = 0;
    for (int i = beg; i < end; i++) s += counts[i];
    partial[tid] = s;
    __syncthreads();
    for (int off = 1; off < 1024; off <<= 1) {
        int v = (tid >= off) ? partial[tid - off] : 0;
        __syncthreads();
        partial[tid] += v;
        __syncthreads();
    }
    int run = (tid == 0) ? 0 : partial[tid - 1];
    for (int i = beg; i < end; i++) {
        offsets[i] = run;
        cursor[i] = run;
        run += counts[i];
    }
    if (tid == 1023) offsets[N] = partial[1023];
}

__global__ void fill_kernel(const int* __restrict__ src, const int* __restrict__ dst,
                            const float* __restrict__ dinv, int* __restrict__ cursor,
                            int* __restrict__ csr_src, float* __restrict__ csr_w, int E) {
    int e = blockIdx.x * blockDim.x + threadIdx.x;
    if (e < E) {
        int s = src[e], d = dst[e];
        int pos = atomicAdd(&cursor[d], 1);
        csr_src[pos] = s;
        csr_w[pos] = dinv[s] * dinv[d];
    }
}

// ---------------- GEMM: H = X @ W  (X:[N,128], W:[128,128]) ----------------

__launch_bounds__(256)
__global__ void gemm_kernel(const float* __restrict__ X, const float* __restrict__ W,
                            float* __restrict__ H, int N) {
    __shared__ float ws[DH * DH];     // 64 KB
    __shared__ float xs[32 * DH];     // 16 KB
    int tid = threadIdx.x;
    const float4* W4 = (const float4*)W;
    float4* ws4 = (float4*)ws;
    #pragma unroll
    for (int i = 0; i < DH * DH / 4 / 256; i++) ws4[tid + i * 256] = W4[tid + i * 256];
    int row0 = blockIdx.x * 32;
    const float4* X4 = (const float4*)X;
    float4* xs4 = (float4*)xs;
    #pragma unroll
    for (int i = 0; i < 4; i++) {
        int li = tid + i * 256;                 // 0..1023
        int lr = li >> 5;                       // local row 0..31
        int q  = li & 31;                       // col quarter
        int r = row0 + lr;
        xs4[li] = (r < N) ? X4[(size_t)r * 32 + q] : make_float4(0.f, 0.f, 0.f, 0.f);
    }
    __syncthreads();

    int cg = tid & 31;   // column group: cols cg*4..cg*4+3
    int rg = tid >> 5;   // row group: rows rg*4..rg*4+3
    float acc[4][4];
    #pragma unroll
    for (int a = 0; a < 4; a++)
        #pragma unroll
        for (int b = 0; b < 4; b++) acc[a][b] = 0.f;

    #pragma unroll 8
    for (int k = 0; k < DH; k++) {
        float4 w = ws4[k * 32 + cg];
        #pragma unroll
        for (int rr = 0; rr < 4; rr++) {
            float xv = xs[(rg * 4 + rr) * DH + k];
            acc[rr][0] += xv * w.x;
            acc[rr][1] += xv * w.y;
            acc[rr][2] += xv * w.z;
            acc[rr][3] += xv * w.w;
        }
    }
    #pragma unroll
    for (int rr = 0; rr < 4; rr++) {
        int r = row0 + rg * 4 + rr;
        if (r < N) {
            float4 o = make_float4(acc[rr][0], acc[rr][1], acc[rr][2], acc[rr][3]);
            ((float4*)(H + (size_t)r * DH))[cg] = o;
        }
    }
}

// ---------------- Aggregation: out[n] = sum_e w_e * H[src_e] + dinv^2[n]*H[n] + b ----------------

__launch_bounds__(256)
__global__ void agg_kernel(const float* __restrict__ H, const int* __restrict__ offsets,
                           const int* __restrict__ csr_src, const float* __restrict__ csr_w,
                           const float* __restrict__ dinv, const float* __restrict__ bias,
                           float* __restrict__ out, int N) {
    int n = blockIdx.x * 4 + (threadIdx.x >> 6);
    int lane = threadIdx.x & 63;
    if (n >= N) return;
    int beg = offsets[n], end = offsets[n + 1];
    const float2* H2 = (const float2*)H;
    float ax = 0.f, ay = 0.f;
    for (int e = beg; e < end; e++) {
        int s = csr_src[e];
        float w = csr_w[e];
        float2 hv = H2[(size_t)s * 64 + lane];
        ax += hv.x * w;
        ay += hv.y * w;
    }
    float sw = dinv[n] * dinv[n];
    float2 hn = H2[(size_t)n * 64 + lane];
    float2 b = ((const float2*)bias)[lane];
    ax += hn.x * sw + b.x;
    ay += hn.y * sw + b.y;
    ((float2*)out)[(size_t)n * 64 + lane] = make_float2(ax, ay);
}

// ---------------- BatchNorm stats (sum, sumsq per feature) ----------------

__launch_bounds__(256)
__global__ void bnstats_kernel(const float* __restrict__ A, float* __restrict__ acc, int N) {
    int f = threadIdx.x & 127;
    int rh = threadIdx.x >> 7;
    float s = 0.f, sq = 0.f;
    for (int r = blockIdx.x * 2 + rh; r < N; r += gridDim.x * 2) {
        float v = A[(size_t)r * DH + f];
        s += v;
        sq += v * v;
    }
    __shared__ float ls[256], lq[256];
    ls[threadIdx.x] = s;
    lq[threadIdx.x] = sq;
    __syncthreads();
    if (threadIdx.x < 128) {
        atomicAdd(&acc[f], ls[threadIdx.x] + ls[threadIdx.x + 128]);
        atomicAdd(&acc[128 + f], lq[threadIdx.x] + lq[threadIdx.x + 128]);
    }
}

// ---------------- BatchNorm apply + ReLU ----------------

__launch_bounds__(256)
__global__ void bnapply_kernel(const float* __restrict__ A, const float* __restrict__ acc,
                               const float* __restrict__ gamma, const float* __restrict__ beta,
                               float* __restrict__ out, int N) {
    int gid = blockIdx.x * blockDim.x + threadIdx.x;  // one float4 each
    int total = N * DH / 4;
    if (gid >= total) return;
    int c = (gid & 31) * 4;
    float4 v = ((const float4*)A)[gid];
    float invN = 1.0f / (float)N;
    float o[4];
    float vv[4] = {v.x, v.y, v.z, v.w};
    #pragma unroll
    for (int j = 0; j < 4; j++) {
        float mean = acc[c + j] * invN;
        float var = acc[128 + c + j] * invN - mean * mean;
        float scale = gamma[c + j] * rsqrtf(var + BN_EPS);
        float y = (vv[j] - mean) * scale + beta[c + j];
        o[j] = fmaxf(y, 0.f);
    }
    ((float4*)out)[gid] = make_float4(o[0], o[1], o[2], o[3]);
}

// ---------------- Pooling (mean over sorted batch segments) ----------------

__device__ __forceinline__ int lower_bound_dev(const int* __restrict__ a, int n, int key) {
    int lo = 0, hi = n;
    while (lo < hi) {
        int m = (lo + hi) >> 1;
        if (a[m] < key) lo = m + 1; else hi = m;
    }
    return lo;
}

__launch_bounds__(256)
__global__ void pool_kernel(const float* __restrict__ ACT, const int* __restrict__ batch,
                            float* __restrict__ pooled, int N) {
    int g = blockIdx.x;
    __shared__ int sbeg, send;
    if (threadIdx.x == 0) {
        sbeg = lower_bound_dev(batch, N, g);
        send = lower_bound_dev(batch, N, g + 1);
    }
    __syncthreads();
    int beg = sbeg, end = send;
    int f = threadIdx.x & 127;
    int rh = threadIdx.x >> 7;
    float s = 0.f;
    for (int r = beg + rh; r < end; r += 2) s += ACT[(size_t)r * DH + f];
    __shared__ float ls[256];
    ls[threadIdx.x] = s;
    __syncthreads();
    if (threadIdx.x < 128) {
        float tot = ls[threadIdx.x] + ls[threadIdx.x + 128];
        float cnt = (float)(end - beg);
        pooled[g * DH + f] = tot / fmaxf(cnt, 1.f);
    }
}

// ---------------- Final linear: out = pooled @ Wl + bl ----------------

__launch_bounds__(256)
__global__ void final_kernel(const float* __restrict__ pooled, const float* __restrict__ Wl,
                             const float* __restrict__ bl, float* __restrict__ out) {
    int gid = blockIdx.x * blockDim.x + threadIdx.x;
    if (gid >= NGRAPH * NCLS) return;
    int g = gid / NCLS, c = gid % NCLS;
    float s = bl[c];
    #pragma unroll 8
    for (int k = 0; k < DH; k++) s += pooled[g * DH + k] * Wl[k * NCLS + c];
    out[gid] = s;
}

// ---------------- Launch ----------------

extern "C" void kernel_launch(void* const* d_in, const int* in_sizes, int n_in,
                              void* d_out, int out_size, void* d_ws, size_t ws_size,
                              hipStream_t stream) {
    const float* x     = (const float*)d_in[0];
    const int*   edges = (const int*)d_in[1];
    const int*   batch = (const int*)d_in[2];
    const float* W1    = (const float*)d_in[3];
    const float* b1    = (const float*)d_in[4];
    const float* g1    = (const float*)d_in[5];
    const float* be1   = (const float*)d_in[6];
    const float* Wc    = (const float*)d_in[7];
    const float* bc    = (const float*)d_in[8];
    const float* gc    = (const float*)d_in[9];
    const float* bec   = (const float*)d_in[10];
    const float* Wl    = (const float*)d_in[11];
    const float* bl    = (const float*)d_in[12];
    float* out = (float*)d_out;

    const int* esrc = edges;
    const int* edst = edges + NE;

    char* w = (char*)d_ws;
    auto alloc = [&](size_t bytes) -> void* {
        void* p = (void*)w;
        w += (bytes + 255) & ~(size_t)255;
        return p;
    };
    int*   counts  = (int*)alloc(NN * 4);
    int*   offsets = (int*)alloc((NN + 1) * 4);
    int*   cursor  = (int*)alloc(NN * 4);
    float* dinv    = (float*)alloc(NN * 4);
    int*   csr_src = (int*)alloc(NE * 4);
    float* csr_w   = (float*)alloc(NE * 4);
    float* bn_acc  = (float*)alloc(256 * 4);
    float* pooled  = (float*)alloc(NGRAPH * DH * 4);
    float* H       = (float*)alloc((size_t)NN * DH * 4);
    float* AGG     = (float*)alloc((size_t)NN * DH * 4);
    float* ACT     = (float*)alloc((size_t)NN * DH * 4);

    hipMemsetAsync(counts, 0, NN * 4, stream);
    hist_kernel<<<(NE + 255) / 256, 256, 0, stream>>>(edst, counts, NE);
    compute_dinv_kernel<<<(NN + 255) / 256, 256, 0, stream>>>(counts, dinv, NN);
    scan_kernel<<<1, 1024, 0, stream>>>(counts, offsets, cursor, NN);
    fill_kernel<<<(NE + 255) / 256, 256, 0, stream>>>(esrc, edst, dinv, cursor, csr_src, csr_w, NE);

    const float* act = x;
    for (int l = 0; l < 4; l++) {
        const float* Wm = (l == 0) ? W1 : Wc + (size_t)(l - 1) * DH * DH;
        const float* bm = (l == 0) ? b1 : bc + (size_t)(l - 1) * DH;
        const float* gm = (l == 0) ? g1 : gc + (size_t)(l - 1) * DH;
        const float* bem = (l == 0) ? be1 : bec + (size_t)(l - 1) * DH;

        gemm_kernel<<<(NN + 31) / 32, 256, 0, stream>>>(act, Wm, H, NN);
        agg_kernel<<<(NN + 3) / 4, 256, 0, stream>>>(H, offsets, csr_src, csr_w, dinv, bm, AGG, NN);
        hipMemsetAsync(bn_acc, 0, 256 * 4, stream);
        bnstats_kernel<<<256, 256, 0, stream>>>(AGG, bn_acc, NN);
        bnapply_kernel<<<(NN * DH / 4 + 255) / 256, 256, 0, stream>>>(AGG, bn_acc, gm, bem, ACT, NN);
        act = ACT;
    }

    pool_kernel<<<NGRAPH, 256, 0, stream>>>(ACT, batch, pooled, NN);
    final_kernel<<<(NGRAPH * NCLS + 255) / 256, 256, 0, stream>>>(pooled, Wl, bl, out);
}

// Round 2
// 728.318 us; speedup vs baseline: 1.1943x; 1.1943x over previous
//
#include <hip/hip_runtime.h>
#include <hip/hip_bf16.h>

#define NN 50000
#define NE 800000
#define DH 128
#define NGRAPH 512
#define NCLS 10
#define BN_EPS 1e-5f
#define SCAN_NB ((NN + 255) / 256)   // 196

// ---------------- CSR build ----------------

__global__ void hist_kernel(const int* __restrict__ dst, int* __restrict__ counts, int E) {
    int e = blockIdx.x * blockDim.x + threadIdx.x;
    if (e < E) atomicAdd(&counts[dst[e]], 1);
}

__global__ void compute_dinv_kernel(const int* __restrict__ counts, float* __restrict__ dinv, int N) {
    int n = blockIdx.x * blockDim.x + threadIdx.x;
    if (n < N) dinv[n] = rsqrtf((float)(counts[n] + 1));
}

// parallel scan: per-block sums
__launch_bounds__(256)
__global__ void scan1_kernel(const int* __restrict__ counts, int* __restrict__ bsum, int N) {
    __shared__ int ls[256];
    int i = blockIdx.x * 256 + threadIdx.x;
    ls[threadIdx.x] = (i < N) ? counts[i] : 0;
    __syncthreads();
    for (int off = 128; off > 0; off >>= 1) {
        if (threadIdx.x < off) ls[threadIdx.x] += ls[threadIdx.x + off];
        __syncthreads();
    }
    if (threadIdx.x == 0) bsum[blockIdx.x] = ls[0];
}

// exclusive scan of block sums (single small block)
__launch_bounds__(256)
__global__ void scan2_kernel(int* __restrict__ bsum, int NB) {
    __shared__ int ls[256];
    int tid = threadIdx.x;
    int v = (tid < NB) ? bsum[tid] : 0;
    ls[tid] = v;
    __syncthreads();
    for (int off = 1; off < 256; off <<= 1) {
        int t = (tid >= off) ? ls[tid - off] : 0;
        __syncthreads();
        ls[tid] += t;
        __syncthreads();
    }
    if (tid < NB) bsum[tid] = ls[tid] - v;   // exclusive
}

// final: block-local scan + block offset -> offsets/cursor
__launch_bounds__(256)
__global__ void scan3_kernel(const int* __restrict__ counts, const int* __restrict__ boff,
                             int* __restrict__ offsets, int* __restrict__ cursor, int N) {
    __shared__ int ls[256];
    int tid = threadIdx.x;
    int i = blockIdx.x * 256 + tid;
    int v = (i < N) ? counts[i] : 0;
    ls[tid] = v;
    __syncthreads();
    for (int off = 1; off < 256; off <<= 1) {
        int t = (tid >= off) ? ls[tid - off] : 0;
        __syncthreads();
        ls[tid] += t;
        __syncthreads();
    }
    int base = boff[blockIdx.x];
    if (i < N) {
        int ex = base + ls[tid] - v;
        offsets[i] = ex;
        cursor[i] = ex;
        if (i == N - 1) offsets[N] = base + ls[tid];
    }
}

__global__ void fill_kernel(const int* __restrict__ src, const int* __restrict__ dst,
                            int* __restrict__ cursor, int* __restrict__ csr_src, int E) {
    int e = blockIdx.x * blockDim.x + threadIdx.x;
    if (e < E) {
        int d = dst[e];
        int pos = atomicAdd(&cursor[d], 1);
        csr_src[pos] = src[e];
    }
}

// ---------------- GEMM: H' = f(X) @ W, rows scaled by dinv ----------------
// MODE==0: X used raw. MODE==1: X passed through BN(affine from bnacc)+ReLU inline.

template<int MODE>
__launch_bounds__(256)
__global__ void gemm_kernel(const float* __restrict__ X, const float* __restrict__ W,
                            const float* __restrict__ bnacc, const float* __restrict__ gamma,
                            const float* __restrict__ beta, const float* __restrict__ dinv,
                            float* __restrict__ H, int N) {
    __shared__ float ws[DH * DH];     // 64 KB
    __shared__ float xs[32 * DH];     // 16 KB
    int tid = threadIdx.x;
    int q = tid & 31;                 // this thread stages features 4q..4q+3 only

    float sc[4], sh[4];
    if (MODE) {
        const float invN = 1.0f / (float)NN;
        #pragma unroll
        for (int j = 0; j < 4; j++) {
            int f = 4 * q + j;
            float mean = bnacc[f] * invN;
            float var = bnacc[128 + f] * invN - mean * mean;
            float s = gamma[f] * rsqrtf(var + BN_EPS);
            sc[j] = s;
            sh[j] = beta[f] - mean * s;
        }
    }

    const float4* W4 = (const float4*)W;
    float4* ws4 = (float4*)ws;
    #pragma unroll
    for (int i = 0; i < DH * DH / 4 / 256; i++) ws4[tid + i * 256] = W4[tid + i * 256];

    int row0 = blockIdx.x * 32;
    const float4* X4 = (const float4*)X;
    float4* xs4 = (float4*)xs;
    #pragma unroll
    for (int i = 0; i < 4; i++) {
        int li = tid + i * 256;                 // 0..1023
        int lr = li >> 5;                       // local row 0..31
        int r = row0 + lr;
        float4 v = (r < N) ? X4[(size_t)r * 32 + q] : make_float4(0.f, 0.f, 0.f, 0.f);
        if (MODE) {
            v.x = fmaxf(v.x * sc[0] + sh[0], 0.f);
            v.y = fmaxf(v.y * sc[1] + sh[1], 0.f);
            v.z = fmaxf(v.z * sc[2] + sh[2], 0.f);
            v.w = fmaxf(v.w * sc[3] + sh[3], 0.f);
        }
        xs4[li] = v;
    }
    __syncthreads();

    int cg = tid & 31;   // column group: cols cg*4..cg*4+3
    int rg = tid >> 5;   // row group: rows rg*4..rg*4+3
    float acc[4][4];
    #pragma unroll
    for (int a = 0; a < 4; a++)
        #pragma unroll
        for (int b = 0; b < 4; b++) acc[a][b] = 0.f;

    #pragma unroll 8
    for (int k = 0; k < DH; k++) {
        float4 w = ws4[k * 32 + cg];
        #pragma unroll
        for (int rr = 0; rr < 4; rr++) {
            float xv = xs[(rg * 4 + rr) * DH + k];
            acc[rr][0] += xv * w.x;
            acc[rr][1] += xv * w.y;
            acc[rr][2] += xv * w.z;
            acc[rr][3] += xv * w.w;
        }
    }
    #pragma unroll
    for (int rr = 0; rr < 4; rr++) {
        int r = row0 + rg * 4 + rr;
        if (r < N) {
            float dv = dinv[r];
            float4 o = make_float4(acc[rr][0] * dv, acc[rr][1] * dv,
                                   acc[rr][2] * dv, acc[rr][3] * dv);
            ((float4*)(H + (size_t)r * DH))[cg] = o;
        }
    }
}

// ---------------- Aggregation: out[n] = dinv[n]*(sum_e H'[src_e] + H'[n]) + b ----------------

__launch_bounds__(256)
__global__ void agg_kernel(const float* __restrict__ H, const int* __restrict__ offsets,
                           const int* __restrict__ csr_src, const float* __restrict__ dinv,
                           const float* __restrict__ bias, float* __restrict__ out, int N) {
    int n = blockIdx.x * 4 + (threadIdx.x >> 6);
    int lane = threadIdx.x & 63;
    if (n >= N) return;
    int beg = offsets[n], end = offsets[n + 1];
    const float2* H2 = (const float2*)H;
    float ax = 0.f, ay = 0.f;
    for (int e = beg; e < end; e++) {
        int s = csr_src[e];
        float2 hv = H2[(size_t)s * 64 + lane];
        ax += hv.x;
        ay += hv.y;
    }
    float2 hn = H2[(size_t)n * 64 + lane];
    ax += hn.x;
    ay += hn.y;
    float dv = dinv[n];
    float2 b = ((const float2*)bias)[lane];
    ((float2*)out)[(size_t)n * 64 + lane] = make_float2(ax * dv + b.x, ay * dv + b.y);
}

// ---------------- BatchNorm stats (sum, sumsq per feature) ----------------

__launch_bounds__(256)
__global__ void bnstats_kernel(const float* __restrict__ A, float* __restrict__ acc, int N) {
    int f = threadIdx.x & 127;
    int rh = threadIdx.x >> 7;
    float s = 0.f, sq = 0.f;
    for (int r = blockIdx.x * 2 + rh; r < N; r += gridDim.x * 2) {
        float v = A[(size_t)r * DH + f];
        s += v;
        sq += v * v;
    }
    __shared__ float ls[256], lq[256];
    ls[threadIdx.x] = s;
    lq[threadIdx.x] = sq;
    __syncthreads();
    if (threadIdx.x < 128) {
        atomicAdd(&acc[f], ls[threadIdx.x] + ls[threadIdx.x + 128]);
        atomicAdd(&acc[128 + f], lq[threadIdx.x] + lq[threadIdx.x + 128]);
    }
}

// ---------------- Pooling with fused BN+ReLU ----------------

__device__ __forceinline__ int lower_bound_dev(const int* __restrict__ a, int n, int key) {
    int lo = 0, hi = n;
    while (lo < hi) {
        int m = (lo + hi) >> 1;
        if (a[m] < key) lo = m + 1; else hi = m;
    }
    return lo;
}

__launch_bounds__(256)
__global__ void pool_kernel(const float* __restrict__ AGG, const int* __restrict__ batch,
                            const float* __restrict__ bnacc, const float* __restrict__ gamma,
                            const float* __restrict__ beta, float* __restrict__ pooled, int N) {
    int g = blockIdx.x;
    __shared__ int sbeg, send;
    if (threadIdx.x == 0) {
        sbeg = lower_bound_dev(batch, N, g);
        send = lower_bound_dev(batch, N, g + 1);
    }
    __syncthreads();
    int beg = sbeg, end = send;
    int f = threadIdx.x & 127;
    int rh = threadIdx.x >> 7;
    const float invN = 1.0f / (float)NN;
    float mean = bnacc[f] * invN;
    float var = bnacc[128 + f] * invN - mean * mean;
    float sc = gamma[f] * rsqrtf(var + BN_EPS);
    float shf = beta[f] - mean * sc;
    float s = 0.f;
    for (int r = beg + rh; r < end; r += 2)
        s += fmaxf(AGG[(size_t)r * DH + f] * sc + shf, 0.f);
    __shared__ float ls[256];
    ls[threadIdx.x] = s;
    __syncthreads();
    if (threadIdx.x < 128) {
        float tot = ls[threadIdx.x] + ls[threadIdx.x + 128];
        float cnt = (float)(end - beg);
        pooled[g * DH + f] = tot / fmaxf(cnt, 1.f);
    }
}

// ---------------- Final linear: out = pooled @ Wl + bl ----------------

__launch_bounds__(256)
__global__ void final_kernel(const float* __restrict__ pooled, const float* __restrict__ Wl,
                             const float* __restrict__ bl, float* __restrict__ out) {
    int gid = blockIdx.x * blockDim.x + threadIdx.x;
    if (gid >= NGRAPH * NCLS) return;
    int g = gid / NCLS, c = gid % NCLS;
    float s = bl[c];
    #pragma unroll 8
    for (int k = 0; k < DH; k++) s += pooled[g * DH + k] * Wl[k * NCLS + c];
    out[gid] = s;
}

// ---------------- Launch ----------------

extern "C" void kernel_launch(void* const* d_in, const int* in_sizes, int n_in,
                              void* d_out, int out_size, void* d_ws, size_t ws_size,
                              hipStream_t stream) {
    const float* x     = (const float*)d_in[0];
    const int*   edges = (const int*)d_in[1];
    const int*   batch = (const int*)d_in[2];
    const float* W1    = (const float*)d_in[3];
    const float* b1    = (const float*)d_in[4];
    const float* g1    = (const float*)d_in[5];
    const float* be1   = (const float*)d_in[6];
    const float* Wc    = (const float*)d_in[7];
    const float* bc    = (const float*)d_in[8];
    const float* gc    = (const float*)d_in[9];
    const float* bec   = (const float*)d_in[10];
    const float* Wl    = (const float*)d_in[11];
    const float* bl    = (const float*)d_in[12];
    float* out = (float*)d_out;

    const int* esrc = edges;
    const int* edst = edges + NE;

    char* w = (char*)d_ws;
    auto alloc = [&](size_t bytes) -> void* {
        void* p = (void*)w;
        w += (bytes + 255) & ~(size_t)255;
        return p;
    };
    int*   counts  = (int*)alloc(NN * 4);
    int*   offsets = (int*)alloc((NN + 1) * 4);
    int*   cursor  = (int*)alloc(NN * 4);
    float* dinv    = (float*)alloc(NN * 4);
    int*   csr_src = (int*)alloc(NE * 4);
    int*   bsum    = (int*)alloc(256 * 4);
    float* bn_acc  = (float*)alloc(256 * 4);
    float* pooled  = (float*)alloc(NGRAPH * DH * 4);
    float* H       = (float*)alloc((size_t)NN * DH * 4);
    float* AGG     = (float*)alloc((size_t)NN * DH * 4);

    hipMemsetAsync(counts, 0, NN * 4, stream);
    hist_kernel<<<(NE + 255) / 256, 256, 0, stream>>>(edst, counts, NE);
    compute_dinv_kernel<<<(NN + 255) / 256, 256, 0, stream>>>(counts, dinv, NN);
    scan1_kernel<<<SCAN_NB, 256, 0, stream>>>(counts, bsum, NN);
    scan2_kernel<<<1, 256, 0, stream>>>(bsum, SCAN_NB);
    scan3_kernel<<<SCAN_NB, 256, 0, stream>>>(counts, bsum, offsets, cursor, NN);
    fill_kernel<<<(NE + 255) / 256, 256, 0, stream>>>(esrc, edst, cursor, csr_src, NE);

    const float* act = x;
    for (int l = 0; l < 4; l++) {
        const float* Wm  = (l == 0) ? W1 : Wc + (size_t)(l - 1) * DH * DH;
        const float* bm  = (l == 0) ? b1 : bc + (size_t)(l - 1) * DH;
        // BN params of PREVIOUS layer (applied to this gemm's input)
        const float* gp  = (l == 1) ? g1 : gc + (size_t)(l - 2) * DH;
        const float* bep = (l == 1) ? be1 : bec + (size_t)(l - 2) * DH;

        if (l == 0) {
            gemm_kernel<0><<<(NN + 31) / 32, 256, 0, stream>>>(
                act, Wm, nullptr, nullptr, nullptr, dinv, H, NN);
        } else {
            gemm_kernel<1><<<(NN + 31) / 32, 256, 0, stream>>>(
                act, Wm, bn_acc, gp, bep, dinv, H, NN);
        }
        agg_kernel<<<(NN + 3) / 4, 256, 0, stream>>>(H, offsets, csr_src, dinv, bm, AGG, NN);
        hipMemsetAsync(bn_acc, 0, 256 * 4, stream);
        bnstats_kernel<<<256, 256, 0, stream>>>(AGG, bn_acc, NN);
        act = AGG;   // next gemm reads raw AGG and applies BN inline
    }

    pool_kernel<<<NGRAPH, 256, 0, stream>>>(AGG, batch, bn_acc, gc + 2 * DH, bec + 2 * DH,
                                            pooled, NN);
    final_kernel<<<(NGRAPH * NCLS + 255) / 256, 256, 0, stream>>>(pooled, Wl, bl, out);
}

// Round 3
// 598.540 us; speedup vs baseline: 1.4532x; 1.2168x over previous
//
#include <hip/hip_runtime.h>
#include <hip/hip_bf16.h>

#define NN 50000
#define NE 800000
#define DH 128
#define NGRAPH 512
#define NCLS 10
#define BN_EPS 1e-5f
#define SCAN_NB ((NN + 255) / 256)   // 196

typedef unsigned int uint;

// ---------------- CSR build ----------------

__global__ void hist_kernel(const int* __restrict__ dst, int* __restrict__ counts, int E) {
    int e = blockIdx.x * blockDim.x + threadIdx.x;
    if (e < E) atomicAdd(&counts[dst[e]], 1);
}

__global__ void compute_dinv_kernel(const int* __restrict__ counts, float* __restrict__ dinv, int N) {
    int n = blockIdx.x * blockDim.x + threadIdx.x;
    if (n < N) dinv[n] = rsqrtf((float)(counts[n] + 1));
}

__launch_bounds__(256)
__global__ void scan1_kernel(const int* __restrict__ counts, int* __restrict__ bsum, int N) {
    __shared__ int ls[256];
    int i = blockIdx.x * 256 + threadIdx.x;
    ls[threadIdx.x] = (i < N) ? counts[i] : 0;
    __syncthreads();
    for (int off = 128; off > 0; off >>= 1) {
        if (threadIdx.x < off) ls[threadIdx.x] += ls[threadIdx.x + off];
        __syncthreads();
    }
    if (threadIdx.x == 0) bsum[blockIdx.x] = ls[0];
}

__launch_bounds__(256)
__global__ void scan2_kernel(int* __restrict__ bsum, int NB) {
    __shared__ int ls[256];
    int tid = threadIdx.x;
    int v = (tid < NB) ? bsum[tid] : 0;
    ls[tid] = v;
    __syncthreads();
    for (int off = 1; off < 256; off <<= 1) {
        int t = (tid >= off) ? ls[tid - off] : 0;
        __syncthreads();
        ls[tid] += t;
        __syncthreads();
    }
    if (tid < NB) bsum[tid] = ls[tid] - v;   // exclusive
}

__launch_bounds__(256)
__global__ void scan3_kernel(const int* __restrict__ counts, const int* __restrict__ boff,
                             int* __restrict__ offsets, int* __restrict__ cursor, int N) {
    __shared__ int ls[256];
    int tid = threadIdx.x;
    int i = blockIdx.x * 256 + tid;
    int v = (i < N) ? counts[i] : 0;
    ls[tid] = v;
    __syncthreads();
    for (int off = 1; off < 256; off <<= 1) {
        int t = (tid >= off) ? ls[tid - off] : 0;
        __syncthreads();
        ls[tid] += t;
        __syncthreads();
    }
    int base = boff[blockIdx.x];
    if (i < N) {
        int ex = base + ls[tid] - v;
        offsets[i] = ex;
        cursor[i] = ex;
        if (i == N - 1) offsets[N] = base + ls[tid];
    }
}

__global__ void fill_kernel(const int* __restrict__ src, const int* __restrict__ dst,
                            int* __restrict__ cursor, int* __restrict__ csr_src, int E) {
    int e = blockIdx.x * blockDim.x + threadIdx.x;
    if (e < E) {
        int d = dst[e];
        int pos = atomicAdd(&cursor[d], 1);
        csr_src[pos] = src[e];
    }
}

// ---------------- GEMM: H' = f(X) @ W, rows scaled by dinv, output bf16 ----------------
// MODE==0: X used raw. MODE==1: X passed through BN(affine from bnacc)+ReLU inline.

template<int MODE>
__launch_bounds__(256)
__global__ void gemm_kernel(const float* __restrict__ X, const float* __restrict__ W,
                            const float* __restrict__ bnacc, const float* __restrict__ gamma,
                            const float* __restrict__ beta, const float* __restrict__ dinv,
                            uint* __restrict__ H, int N) {
    __shared__ float ws[DH * DH];     // 64 KB
    __shared__ float xs[32 * DH];     // 16 KB
    int tid = threadIdx.x;
    int q = tid & 31;                 // this thread stages features 4q..4q+3 only

    float sc[4], sh[4];
    if (MODE) {
        const float invN = 1.0f / (float)NN;
        #pragma unroll
        for (int j = 0; j < 4; j++) {
            int f = 4 * q + j;
            float mean = bnacc[f] * invN;
            float var = bnacc[128 + f] * invN - mean * mean;
            float s = gamma[f] * rsqrtf(var + BN_EPS);
            sc[j] = s;
            sh[j] = beta[f] - mean * s;
        }
    }

    const float4* W4 = (const float4*)W;
    float4* ws4 = (float4*)ws;
    #pragma unroll
    for (int i = 0; i < DH * DH / 4 / 256; i++) ws4[tid + i * 256] = W4[tid + i * 256];

    int row0 = blockIdx.x * 32;
    const float4* X4 = (const float4*)X;
    float4* xs4 = (float4*)xs;
    #pragma unroll
    for (int i = 0; i < 4; i++) {
        int li = tid + i * 256;                 // 0..1023
        int lr = li >> 5;                       // local row 0..31
        int r = row0 + lr;
        float4 v = (r < N) ? X4[(size_t)r * 32 + q] : make_float4(0.f, 0.f, 0.f, 0.f);
        if (MODE) {
            v.x = fmaxf(v.x * sc[0] + sh[0], 0.f);
            v.y = fmaxf(v.y * sc[1] + sh[1], 0.f);
            v.z = fmaxf(v.z * sc[2] + sh[2], 0.f);
            v.w = fmaxf(v.w * sc[3] + sh[3], 0.f);
        }
        xs4[li] = v;
    }
    __syncthreads();

    int cg = tid & 31;   // column group: cols cg*4..cg*4+3
    int rg = tid >> 5;   // row group: rows rg*4..rg*4+3
    float acc[4][4];
    #pragma unroll
    for (int a = 0; a < 4; a++)
        #pragma unroll
        for (int b = 0; b < 4; b++) acc[a][b] = 0.f;

    #pragma unroll 8
    for (int k = 0; k < DH; k++) {
        float4 w = ws4[k * 32 + cg];
        #pragma unroll
        for (int rr = 0; rr < 4; rr++) {
            float xv = xs[(rg * 4 + rr) * DH + k];
            acc[rr][0] += xv * w.x;
            acc[rr][1] += xv * w.y;
            acc[rr][2] += xv * w.z;
            acc[rr][3] += xv * w.w;
        }
    }
    #pragma unroll
    for (int rr = 0; rr < 4; rr++) {
        int r = row0 + rg * 4 + rr;
        if (r < N) {
            float dv = dinv[r];
            __hip_bfloat162 p0 = __float22bfloat162_rn(float2{acc[rr][0] * dv, acc[rr][1] * dv});
            __hip_bfloat162 p1 = __float22bfloat162_rn(float2{acc[rr][2] * dv, acc[rr][3] * dv});
            uint2 o;
            o.x = *(uint*)&p0;
            o.y = *(uint*)&p1;
            ((uint2*)(H + (size_t)r * 64))[cg] = o;
        }
    }
}

// ---------------- Aggregation: out[n] = dinv[n]*(sum_e H'[src_e] + H'[n]) + b ----------------
// H' is bf16-packed: uint at [n*64+lane] = features {2*lane, 2*lane+1}

__device__ __forceinline__ float bf_lo(uint v) { return __uint_as_float(v << 16); }
__device__ __forceinline__ float bf_hi(uint v) { return __uint_as_float(v & 0xffff0000u); }

__launch_bounds__(256)
__global__ void agg_kernel(const uint* __restrict__ H, const int* __restrict__ offsets,
                           const int* __restrict__ csr_src, const float* __restrict__ dinv,
                           const float* __restrict__ bias, float* __restrict__ out, int N) {
    int n = blockIdx.x * 4 + (threadIdx.x >> 6);
    int lane = threadIdx.x & 63;
    if (n >= N) return;
    int beg = offsets[n], end = offsets[n + 1];
    float ax = 0.f, ay = 0.f;
    int e = beg;
    for (; e + 1 < end; e += 2) {
        int s0 = csr_src[e];
        int s1 = csr_src[e + 1];
        uint v0 = H[(size_t)s0 * 64 + lane];
        uint v1 = H[(size_t)s1 * 64 + lane];
        ax += bf_lo(v0);
        ay += bf_hi(v0);
        ax += bf_lo(v1);
        ay += bf_hi(v1);
    }
    if (e < end) {
        uint v = H[(size_t)csr_src[e] * 64 + lane];
        ax += bf_lo(v);
        ay += bf_hi(v);
    }
    uint vn = H[(size_t)n * 64 + lane];
    ax += bf_lo(vn);
    ay += bf_hi(vn);
    float dv = dinv[n];
    float2 b = ((const float2*)bias)[lane];
    ((float2*)out)[(size_t)n * 64 + lane] = make_float2(ax * dv + b.x, ay * dv + b.y);
}

// ---------------- BatchNorm stats (sum, sumsq per feature) ----------------

__launch_bounds__(256)
__global__ void bnstats_kernel(const float* __restrict__ A, float* __restrict__ acc, int N) {
    int f = threadIdx.x & 127;
    int rh = threadIdx.x >> 7;
    float s = 0.f, sq = 0.f;
    for (int r = blockIdx.x * 2 + rh; r < N; r += gridDim.x * 2) {
        float v = A[(size_t)r * DH + f];
        s += v;
        sq += v * v;
    }
    __shared__ float ls[256], lq[256];
    ls[threadIdx.x] = s;
    lq[threadIdx.x] = sq;
    __syncthreads();
    if (threadIdx.x < 128) {
        atomicAdd(&acc[f], ls[threadIdx.x] + ls[threadIdx.x + 128]);
        atomicAdd(&acc[128 + f], lq[threadIdx.x] + lq[threadIdx.x + 128]);
    }
}

// ---------------- Pooling with fused BN+ReLU ----------------

__device__ __forceinline__ int lower_bound_dev(const int* __restrict__ a, int n, int key) {
    int lo = 0, hi = n;
    while (lo < hi) {
        int m = (lo + hi) >> 1;
        if (a[m] < key) lo = m + 1; else hi = m;
    }
    return lo;
}

__launch_bounds__(256)
__global__ void pool_kernel(const float* __restrict__ AGG, const int* __restrict__ batch,
                            const float* __restrict__ bnacc, const float* __restrict__ gamma,
                            const float* __restrict__ beta, float* __restrict__ pooled, int N) {
    int g = blockIdx.x;
    __shared__ int sbeg, send;
    if (threadIdx.x == 0) {
        sbeg = lower_bound_dev(batch, N, g);
        send = lower_bound_dev(batch, N, g + 1);
    }
    __syncthreads();
    int beg = sbeg, end = send;
    int f = threadIdx.x & 127;
    int rh = threadIdx.x >> 7;
    const float invN = 1.0f / (float)NN;
    float mean = bnacc[f] * invN;
    float var = bnacc[128 + f] * invN - mean * mean;
    float sc = gamma[f] * rsqrtf(var + BN_EPS);
    float shf = beta[f] - mean * sc;
    float s = 0.f;
    for (int r = beg + rh; r < end; r += 2)
        s += fmaxf(AGG[(size_t)r * DH + f] * sc + shf, 0.f);
    __shared__ float ls[256];
    ls[threadIdx.x] = s;
    __syncthreads();
    if (threadIdx.x < 128) {
        float tot = ls[threadIdx.x] + ls[threadIdx.x + 128];
        float cnt = (float)(end - beg);
        pooled[g * DH + f] = tot / fmaxf(cnt, 1.f);
    }
}

// ---------------- Final linear: out = pooled @ Wl + bl ----------------

__launch_bounds__(256)
__global__ void final_kernel(const float* __restrict__ pooled, const float* __restrict__ Wl,
                             const float* __restrict__ bl, float* __restrict__ out) {
    int gid = blockIdx.x * blockDim.x + threadIdx.x;
    if (gid >= NGRAPH * NCLS) return;
    int g = gid / NCLS, c = gid % NCLS;
    float s = bl[c];
    #pragma unroll 8
    for (int k = 0; k < DH; k++) s += pooled[g * DH + k] * Wl[k * NCLS + c];
    out[gid] = s;
}

// ---------------- Launch ----------------

extern "C" void kernel_launch(void* const* d_in, const int* in_sizes, int n_in,
                              void* d_out, int out_size, void* d_ws, size_t ws_size,
                              hipStream_t stream) {
    const float* x     = (const float*)d_in[0];
    const int*   edges = (const int*)d_in[1];
    const int*   batch = (const int*)d_in[2];
    const float* W1    = (const float*)d_in[3];
    const float* b1    = (const float*)d_in[4];
    const float* g1    = (const float*)d_in[5];
    const float* be1   = (const float*)d_in[6];
    const float* Wc    = (const float*)d_in[7];
    const float* bc    = (const float*)d_in[8];
    const float* gc    = (const float*)d_in[9];
    const float* bec   = (const float*)d_in[10];
    const float* Wl    = (const float*)d_in[11];
    const float* bl    = (const float*)d_in[12];
    float* out = (float*)d_out;

    const int* esrc = edges;
    const int* edst = edges + NE;

    char* w = (char*)d_ws;
    auto alloc = [&](size_t bytes) -> void* {
        void* p = (void*)w;
        w += (bytes + 255) & ~(size_t)255;
        return p;
    };
    int*   counts  = (int*)alloc(NN * 4);
    int*   offsets = (int*)alloc((NN + 1) * 4);
    int*   cursor  = (int*)alloc(NN * 4);
    float* dinv    = (float*)alloc(NN * 4);
    int*   csr_src = (int*)alloc(NE * 4);
    int*   bsum    = (int*)alloc(256 * 4);
    float* bn_acc  = (float*)alloc(256 * 4);
    float* pooled  = (float*)alloc(NGRAPH * DH * 4);
    uint*  H       = (uint*)alloc((size_t)NN * 64 * 4);      // bf16-packed [N,128]
    float* AGG     = (float*)alloc((size_t)NN * DH * 4);

    hipMemsetAsync(counts, 0, NN * 4, stream);
    hist_kernel<<<(NE + 255) / 256, 256, 0, stream>>>(edst, counts, NE);
    compute_dinv_kernel<<<(NN + 255) / 256, 256, 0, stream>>>(counts, dinv, NN);
    scan1_kernel<<<SCAN_NB, 256, 0, stream>>>(counts, bsum, NN);
    scan2_kernel<<<1, 256, 0, stream>>>(bsum, SCAN_NB);
    scan3_kernel<<<SCAN_NB, 256, 0, stream>>>(counts, bsum, offsets, cursor, NN);
    fill_kernel<<<(NE + 255) / 256, 256, 0, stream>>>(esrc, edst, cursor, csr_src, NE);

    const float* act = x;
    for (int l = 0; l < 4; l++) {
        const float* Wm  = (l == 0) ? W1 : Wc + (size_t)(l - 1) * DH * DH;
        const float* bm  = (l == 0) ? b1 : bc + (size_t)(l - 1) * DH;
        const float* gp  = (l == 1) ? g1 : gc + (size_t)(l - 2) * DH;
        const float* bep = (l == 1) ? be1 : bec + (size_t)(l - 2) * DH;

        if (l == 0) {
            gemm_kernel<0><<<(NN + 31) / 32, 256, 0, stream>>>(
                act, Wm, nullptr, nullptr, nullptr, dinv, H, NN);
        } else {
            gemm_kernel<1><<<(NN + 31) / 32, 256, 0, stream>>>(
                act, Wm, bn_acc, gp, bep, dinv, H, NN);
        }
        agg_kernel<<<(NN + 3) / 4, 256, 0, stream>>>(H, offsets, csr_src, dinv, bm, AGG, NN);
        hipMemsetAsync(bn_acc, 0, 256 * 4, stream);
        bnstats_kernel<<<256, 256, 0, stream>>>(AGG, bn_acc, NN);
        act = AGG;   // next gemm reads raw AGG and applies BN inline
    }

    pool_kernel<<<NGRAPH, 256, 0, stream>>>(AGG, batch, bn_acc, gc + 2 * DH, bec + 2 * DH,
                                            pooled, NN);
    final_kernel<<<(NGRAPH * NCLS + 255) / 256, 256, 0, stream>>>(pooled, Wl, bl, out);
}